// Round 2
// baseline (65808.649 us; speedup 1.0000x reference)
//
#include <hip/hip_runtime.h>
#include <math.h>

// ---------------- problem constants ----------------
constexpr int MM = 8;      // batch of GPs
constexpr int NC = 1024;   // context points
constexpr int NT = 512;    // target points

// Workspace layout (floats):
//  Kb   : MM*1024*1024   (K -> G = K^-1)
//  Ab   : MM*1024*1024   (diag-block inverses + A = L^-1; reused as W at predict)
//  Tb   : MM*512*512     (trinv temp)
//  Ktc  : MM*NT*NC
//  alpha: MM*1024
//  scal : MM*32  per-m: [0..3] raw params(ls,os,noise,const) [4..7] adam m
//                       [8..11] adam v [12]ls [13]os [14]noise [15]T1 [16]T2
//  bar  : 512 u32 words (grid barrier state)
constexpr size_t OFF_A     = (size_t)MM * 1024 * 1024;
constexpr size_t OFF_T     = OFF_A * 2;
constexpr size_t OFF_KTC   = OFF_T + (size_t)MM * 512 * 512;
constexpr size_t OFF_ALPHA = OFF_KTC + (size_t)MM * NT * NC;
constexpr size_t OFF_SCAL  = OFF_ALPHA + (size_t)MM * 1024;
constexpr size_t OFF_BAR   = OFF_SCAL + (size_t)MM * 32;

#define S5 2.2360679775f

__device__ __forceinline__ float sigmf(float x) { return 1.0f / (1.0f + expf(-x)); }
__device__ __forceinline__ float softplusf(float x) { return fmaxf(x, 0.0f) + log1pf(expf(-fabsf(x))); }

__device__ __forceinline__ void lt_decode(int x, int& i, int& j) {
  int ii = 0;
  while ((ii + 1) * (ii + 2) / 2 <= x) ++ii;
  i = ii; j = x - ii * (ii + 1) / 2;
}

// Shared-memory union for all phases (~47.5 KB -> 2+ blocks/CU)
struct SMem {
  float Ls[64 * 65];
  float Us[64 * 65];
  float Tt[32 * 33];
  float dvec[64];
  float As[16][68];
  float Bs[16][68];
  float xi[64][3];
  float xj[64][3];
  float ai[64];
  float aj[64];
  float red[4][4];
};

// ---------------- grid barrier (monotonic epochs, 16 padded sub-counters) ----
// bar[idx*16] idx=0..15 sub-counters; bar[256] root; bar[264] generation.
__device__ __forceinline__ void gbar(unsigned* bar, int nblk, int& epoch) {
  __syncthreads();
  if (threadIdx.x == 0) {
    unsigned e1 = (unsigned)(epoch + 1);
    __threadfence();
    unsigned per = (unsigned)(nblk >> 4);           // nblk is a multiple of 16
    unsigned* ctr = bar + ((blockIdx.x & 15) << 4); // 64B-padded counters
    unsigned old = __hip_atomic_fetch_add(ctr, 1u, __ATOMIC_ACQ_REL, __HIP_MEMORY_SCOPE_AGENT);
    if (old + 1u == per * e1) {
      unsigned r = __hip_atomic_fetch_add(bar + 256, 1u, __ATOMIC_ACQ_REL, __HIP_MEMORY_SCOPE_AGENT);
      if (r + 1u == 16u * e1) {
        __hip_atomic_store(bar + 264, e1, __ATOMIC_RELEASE, __HIP_MEMORY_SCOPE_AGENT);
      }
    }
    while (__hip_atomic_load(bar + 264, __ATOMIC_ACQUIRE, __HIP_MEMORY_SCOPE_AGENT) < e1) {
      __builtin_amdgcn_s_sleep(2);
    }
    __threadfence();
  }
  __syncthreads();
  epoch += 1;
}

// ---------------- generic 64x64-tile GEMM over K (LDS staged, 4x4 microtile) --
// logical A(r,k): TA ? A[k*lda+r] : A[r*lda+k];  logical B(k,c): TB ? B[c*ldb+k] : B[k*ldb+c]
// kBeg/kEnd multiples of 16.
template <int TA, int TB>
__device__ __forceinline__ void gemm64(const float* __restrict__ A, int lda,
                                       const float* __restrict__ B, int ldb,
                                       int kBeg, int kEnd, float acc[4][4], SMem& sm) {
  int tid = threadIdx.x, tx = tid & 15, ty = tid >> 4;
  for (int k0 = kBeg; k0 < kEnd; k0 += 16) {
    __syncthreads();
    if (TA) {
      for (int e = tid; e < 1024; e += 256) { int kk = e >> 6, r = e & 63; sm.As[kk][r] = A[(size_t)(k0 + kk) * lda + r]; }
    } else {
      for (int e = tid; e < 1024; e += 256) { int r = e >> 4, kk = e & 15; sm.As[kk][r] = A[(size_t)r * lda + k0 + kk]; }
    }
    if (TB) {
      for (int e = tid; e < 1024; e += 256) { int c = e >> 4, kk = e & 15; sm.Bs[kk][c] = B[(size_t)c * ldb + k0 + kk]; }
    } else {
      for (int e = tid; e < 1024; e += 256) { int kk = e >> 6, c = e & 63; sm.Bs[kk][c] = B[(size_t)(k0 + kk) * ldb + c]; }
    }
    __syncthreads();
#pragma unroll
    for (int kk = 0; kk < 16; ++kk) {
      float a[4], b[4];
#pragma unroll
      for (int i = 0; i < 4; ++i) a[i] = sm.As[kk][ty * 4 + i];
#pragma unroll
      for (int j = 0; j < 4; ++j) b[j] = sm.Bs[kk][tx * 4 + j];
#pragma unroll
      for (int i = 0; i < 4; ++i)
#pragma unroll
        for (int j = 0; j < 4; ++j) acc[i][j] = fmaf(a[i], b[j], acc[i][j]);
    }
  }
}

// ---------------- phases ----------------

// Build K lower tiles (diag tiles full square). Also zero alpha and T1/T2.
__device__ void ph_buildK(SMem& sm, const float* xc, float* Kb, const float* scal,
                          float* alpha, float* scal_rw, int n, int nb, int nblk) {
  int tid = threadIdx.x;
  int njobs = 8 * (nb * (nb + 1) / 2);
  for (int job = blockIdx.x; job < njobs; job += nblk) {
    int m = job & 7;
    int bi, bj; lt_decode(job >> 3, bi, bj);
    const float* xm = xc + (size_t)m * NC * 3;
    const float* s = scal + m * 32;
    float ls = s[12], os = s[13], noi = s[14];
    float il2 = 1.0f / (ls * ls);
    __syncthreads();
    if (tid < 64) {
      int r = bi * 64 + tid;
      sm.xi[tid][0] = xm[r * 3 + 0]; sm.xi[tid][1] = xm[r * 3 + 1]; sm.xi[tid][2] = xm[r * 3 + 2];
    } else if (tid < 128) {
      int lr = tid - 64; int r = bj * 64 + lr;
      sm.xj[lr][0] = xm[r * 3 + 0]; sm.xj[lr][1] = xm[r * 3 + 1]; sm.xj[lr][2] = xm[r * 3 + 2];
    }
    __syncthreads();
    float* Km = Kb + (size_t)m * 1048576;
    for (int e = tid; e < 4096; e += 256) {
      int r = e >> 6, c = e & 63;
      float d0 = sm.xi[r][0] - sm.xj[c][0], d1 = sm.xi[r][1] - sm.xj[c][1], d2 = sm.xi[r][2] - sm.xj[c][2];
      float r2 = d0 * d0 + d1 * d1 + d2 * d2;
      float z = fmaxf(r2 * il2, 1e-12f);
      float dd = sqrtf(z);
      float kv = os * (1.0f + S5 * dd + (5.0f / 3.0f) * z) * expf(-S5 * dd);
      int gr = bi * 64 + r, gc = bj * 64 + c;
      if (gr == gc) kv += noi;
      Km[(size_t)gr * n + gc] = kv;
    }
  }
  // zero alpha + T1/T2 accumulators for this step
  for (int i = blockIdx.x * 256 + tid; i < MM * 1024; i += nblk * 256) alpha[i] = 0.0f;
  if (blockIdx.x == 0 && tid < 16) scal_rw[(tid >> 1) * 32 + 15 + (tid & 1)] = 0.0f;
}

// Factor 64x64 diag block (raw-Schur form: 1 barrier/column) + invert -> Ab[k,k]
__device__ void ph_diag(SMem& sm, float* Kb, float* Ab, int k, int n, int nblk) {
  int tid = threadIdx.x;
  for (int job = blockIdx.x; job < 8; job += nblk) {
    int m = job;
    float* Km = Kb + (size_t)m * 1048576 + (size_t)(k * 64) * n + k * 64;
    float* Am = Ab + (size_t)m * 1048576 + (size_t)(k * 64) * n + k * 64;
    __syncthreads();
    for (int e = tid; e < 4096; e += 256) { int r = e >> 6, c = e & 63; sm.Ls[r * 65 + c] = Km[(size_t)r * n + c]; }
    __syncthreads();
    int tx = tid & 15, ty = tid >> 4;
    // raw Schur-complement loop: writes cols > j only, reads col j raw -> race-free with 1 barrier
    for (int j = 0; j < 63; ++j) {
      float rinv = 1.0f / sm.Ls[j * 65 + j];
      for (int i = j + 1 + ty; i < 64; i += 16) {
        float lij = sm.Ls[i * 65 + j] * rinv;
        for (int c = j + 1 + tx; c <= i; c += 16) sm.Ls[i * 65 + c] -= lij * sm.Ls[c * 65 + j];
      }
      __syncthreads();
    }
    // scale columns: L[r][c] = raw[r][c]/sqrt(raw[c][c]) (diag -> sqrt)
    if (tid < 64) sm.dvec[tid] = 1.0f / sqrtf(sm.Ls[tid * 65 + tid]);
    __syncthreads();
    for (int e = tid; e < 4096; e += 256) { int r = e >> 6, c = e & 63; if (c <= r) sm.Ls[r * 65 + c] *= sm.dvec[c]; }
    __syncthreads();
    // invert: Us = L^-1 (two 32x32 base blocks, one doubling step)
    for (int e = tid; e < 64 * 65; e += 256) sm.Us[e] = 0.0f;
    __syncthreads();
    if (tid < 64) {
      int b = tid >> 5, c0 = tid & 31, base = b * 32, gc = base + c0;
      sm.Us[gc * 65 + gc] = 1.0f / sm.Ls[gc * 65 + gc];
      for (int r = c0 + 1; r < 32; ++r) {
        int gr = base + r;
        float acc = 0.0f;
        for (int l = c0; l < r; ++l) acc += sm.Ls[gr * 65 + base + l] * sm.Us[(base + l) * 65 + gc];
        sm.Us[gr * 65 + gc] = -acc / sm.Ls[gr * 65 + gr];
      }
    }
    __syncthreads();
    // T = L21 * U11
    for (int e = tid; e < 1024; e += 256) {
      int r = e >> 5, c = e & 31;
      float acc = 0.0f;
      for (int l = c; l < 32; ++l) acc += sm.Ls[(32 + r) * 65 + l] * sm.Us[l * 65 + c];
      sm.Tt[r * 33 + c] = acc;
    }
    __syncthreads();
    // U21 = -U22 * T
    for (int e = tid; e < 1024; e += 256) {
      int r = e >> 5, c = e & 31;
      float acc = 0.0f;
      for (int l = 0; l <= r; ++l) acc += sm.Us[(32 + r) * 65 + 32 + l] * sm.Tt[l * 33 + c];
      sm.Us[(32 + r) * 65 + c] = -acc;
    }
    __syncthreads();
    for (int e = tid; e < 4096; e += 256) { int r = e >> 6, c = e & 63; Am[(size_t)r * n + c] = sm.Us[r * 65 + c]; }
  }
}

// panel: L[i,k] = K[i,k] * Linv[k,k]^T (in place)
__device__ void ph_panel(SMem& sm, float* Kb, const float* Ab, int k, int n, int t, int nblk) {
  int tx = threadIdx.x & 15, ty = threadIdx.x >> 4;
  int njobs = 8 * t;
  for (int job = blockIdx.x; job < njobs; job += nblk) {
    int m = job & 7, i = k + 1 + (job >> 3);
    float* Km = Kb + (size_t)m * 1048576;
    const float* Am = Ab + (size_t)m * 1048576;
    float acc[4][4] = {};
    gemm64<0, 1>(Km + (size_t)(i * 64) * n + k * 64, n,
                 Am + (size_t)(k * 64) * n + k * 64, n, 0, 64, acc, sm);
    float* C = Km + (size_t)(i * 64) * n + k * 64;
#pragma unroll
    for (int ii = 0; ii < 4; ++ii)
#pragma unroll
      for (int jj = 0; jj < 4; ++jj) C[(size_t)(ty * 4 + ii) * n + tx * 4 + jj] = acc[ii][jj];
  }
}

// trailing: K[i,j] -= L[i,k] * L[j,k]^T
__device__ void ph_trail(SMem& sm, float* Kb, int k, int n, int t, int nblk) {
  int tx = threadIdx.x & 15, ty = threadIdx.x >> 4;
  int njobs = 8 * (t * (t + 1) / 2);
  for (int job = blockIdx.x; job < njobs; job += nblk) {
    int m = job & 7;
    int di, dj; lt_decode(job >> 3, di, dj);
    int i = k + 1 + di, j = k + 1 + dj;
    float* Km = Kb + (size_t)m * 1048576;
    float acc[4][4] = {};
    gemm64<0, 1>(Km + (size_t)(i * 64) * n + k * 64, n,
                 Km + (size_t)(j * 64) * n + k * 64, n, 0, 64, acc, sm);
    float* C = Km + (size_t)(i * 64) * n + j * 64;
#pragma unroll
    for (int ii = 0; ii < 4; ++ii)
#pragma unroll
      for (int jj = 0; jj < 4; ++jj) C[(size_t)(ty * 4 + ii) * n + tx * 4 + jj] -= acc[ii][jj];
  }
}

// trinv phase 1: T = L21 * A11 (A11 block-lower)
__device__ void ph_trinvT(SMem& sm, const float* Kb, const float* Ab, float* Tb, int s, int n, int nblk) {
  int tx = threadIdx.x & 15, ty = threadIdx.x >> 4;
  int st = s >> 6, np = n / (2 * s);
  int njobs = 8 * np * st * st;
  for (int job = blockIdx.x; job < njobs; job += nblk) {
    int m = job & 7, q = job >> 3;
    int p = q / (st * st), rem = q % (st * st);
    int ti = rem / st, tj = rem % st;
    int base = p * 2 * s;
    const float* Km = Kb + (size_t)m * 1048576;
    const float* Am = Ab + (size_t)m * 1048576;
    float acc[4][4] = {};
    gemm64<0, 0>(Km + (size_t)(base + s + ti * 64) * n + base, n,
                 Am + (size_t)base * n + base + tj * 64, n, tj * 64, s, acc, sm);
    float* C = Tb + (size_t)m * 262144 + (size_t)p * s * s + (size_t)(ti * 64) * s + tj * 64;
#pragma unroll
    for (int ii = 0; ii < 4; ++ii)
#pragma unroll
      for (int jj = 0; jj < 4; ++jj) C[(size_t)(ty * 4 + ii) * s + tx * 4 + jj] = acc[ii][jj];
  }
}

// trinv phase 2: A21 = -A22 * T (A22 block-lower)
__device__ void ph_trinvA(SMem& sm, float* Ab, const float* Tb, int s, int n, int nblk) {
  int tx = threadIdx.x & 15, ty = threadIdx.x >> 4;
  int st = s >> 6, np = n / (2 * s);
  int njobs = 8 * np * st * st;
  for (int job = blockIdx.x; job < njobs; job += nblk) {
    int m = job & 7, q = job >> 3;
    int p = q / (st * st), rem = q % (st * st);
    int ti = rem / st, tj = rem % st;
    int base = p * 2 * s;
    float* Am = Ab + (size_t)m * 1048576;
    float acc[4][4] = {};
    gemm64<0, 0>(Am + (size_t)(base + s + ti * 64) * n + base + s, n,
                 Tb + (size_t)m * 262144 + (size_t)p * s * s + tj * 64, s,
                 0, (ti + 1) * 64, acc, sm);
    float* C = Am + (size_t)(base + s + ti * 64) * n + base + tj * 64;
#pragma unroll
    for (int ii = 0; ii < 4; ++ii)
#pragma unroll
      for (int jj = 0; jj < 4; ++jj) C[(size_t)(ty * 4 + ii) * n + tx * 4 + jj] = -acc[ii][jj];
  }
}

// syrk: G = A^T A (A lower-tri), lower tile + mirror
__device__ void ph_syrk(SMem& sm, const float* Ab, float* Kb, int n, int nb, int nblk) {
  int tx = threadIdx.x & 15, ty = threadIdx.x >> 4;
  int njobs = 8 * (nb * (nb + 1) / 2);
  for (int job = blockIdx.x; job < njobs; job += nblk) {
    int m = job & 7;
    int ib, jb; lt_decode(job >> 3, ib, jb);
    const float* Am = Ab + (size_t)m * 1048576;
    float* Gm = Kb + (size_t)m * 1048576;
    float acc[4][4] = {};
    gemm64<1, 0>(Am + ib * 64, n, Am + jb * 64, n, ib * 64, n, acc, sm);
#pragma unroll
    for (int ii = 0; ii < 4; ++ii)
#pragma unroll
      for (int jj = 0; jj < 4; ++jj) {
        int r = ty * 4 + ii, c = tx * 4 + jj;
        Gm[(size_t)(ib * 64 + r) * n + jb * 64 + c] = acc[ii][jj];
        if (ib != jb) Gm[(size_t)(jb * 64 + c) * n + ib * 64 + r] = acc[ii][jj];
      }
  }
}

// alpha += per-column-block contribution of G * (y - const)
__device__ void ph_alpha(SMem& sm, const float* Kb, const float* yc, const float* scal,
                         float* alpha, int n, int nb, int nblk) {
  int tid = threadIdx.x;
  int njobs = 8 * nb;
  int NQ = n >> 8;  // 2 or 4
  for (int job = blockIdx.x; job < njobs; job += nblk) {
    int m = job & 7, cb = job >> 3;
    __syncthreads();
    if (tid < 64) sm.ai[tid] = yc[(size_t)m * NC + cb * 64 + tid] - scal[m * 32 + 3];
    __syncthreads();
    const float* G = Kb + (size_t)m * 1048576;
    float acc[4] = {0.f, 0.f, 0.f, 0.f};
    for (int c = 0; c < 64; ++c) {
      float yv = sm.ai[c];
      const float* row = G + (size_t)(cb * 64 + c) * n;
#pragma unroll
      for (int q = 0; q < 4; ++q)
        if (q < NQ) acc[q] = fmaf(row[tid + (q << 8)], yv, acc[q]);
    }
#pragma unroll
    for (int q = 0; q < 4; ++q)
      if (q < NQ) atomicAdd(&alpha[m * 1024 + tid + (q << 8)], acc[q]);
  }
}

// reduce: T1 = sum G.*C, T2 = alpha^T C alpha (C recomputed on the fly)
__device__ void ph_reduce(SMem& sm, const float* Kb, const float* xc, const float* alpha,
                          float* scal, int n, int nb, int nblk) {
  int tid = threadIdx.x;
  int njobs = 8 * nb * nb;
  for (int job = blockIdx.x; job < njobs; job += nblk) {
    int m = job & 7, q = job >> 3;
    int bi = q / nb, bj = q % nb;
    const float* xm = xc + (size_t)m * NC * 3;
    const float* s = scal + m * 32;
    float ls = s[12], os = s[13];
    float il2 = 1.0f / (ls * ls);
    float c53 = (5.0f / 3.0f) * os / ls;
    __syncthreads();
    if (tid < 64) {
      int r = bi * 64 + tid;
      sm.xi[tid][0] = xm[r * 3 + 0]; sm.xi[tid][1] = xm[r * 3 + 1]; sm.xi[tid][2] = xm[r * 3 + 2];
      sm.ai[tid] = alpha[m * 1024 + r];
    } else if (tid < 128) {
      int lr = tid - 64; int r = bj * 64 + lr;
      sm.xj[lr][0] = xm[r * 3 + 0]; sm.xj[lr][1] = xm[r * 3 + 1]; sm.xj[lr][2] = xm[r * 3 + 2];
      sm.aj[lr] = alpha[m * 1024 + r];
    }
    __syncthreads();
    const float* G = Kb + (size_t)m * 1048576;
    float a1 = 0.0f, a2 = 0.0f;
    for (int e = tid; e < 4096; e += 256) {
      int r = e >> 6, c = e & 63;
      float d0 = sm.xi[r][0] - sm.xj[c][0], d1 = sm.xi[r][1] - sm.xj[c][1], d2 = sm.xi[r][2] - sm.xj[c][2];
      float r2 = d0 * d0 + d1 * d1 + d2 * d2;
      float z = fmaxf(r2 * il2, 1e-12f);
      float dd = sqrtf(z);
      float Cv = c53 * z * (1.0f + S5 * dd) * expf(-S5 * dd);
      float g = G[(size_t)(bi * 64 + r) * n + bj * 64 + c];
      a1 = fmaf(g, Cv, a1);
      a2 = fmaf(sm.ai[r] * sm.aj[c], Cv, a2);
    }
    for (int off = 32; off; off >>= 1) { a1 += __shfl_down(a1, off); a2 += __shfl_down(a2, off); }
    int wid = tid >> 6, lane = tid & 63;
    if (lane == 0) { sm.red[wid][0] = a1; sm.red[wid][1] = a2; }
    __syncthreads();
    if (tid == 0) {
      a1 = sm.red[0][0] + sm.red[1][0] + sm.red[2][0] + sm.red[3][0];
      a2 = sm.red[0][1] + sm.red[1][1] + sm.red[2][1] + sm.red[3][1];
      atomicAdd(&scal[m * 32 + 15], a1);
      atomicAdd(&scal[m * 32 + 16], a2);
    }
  }
}

// adam: finish reductions, compute grads, update params
__device__ void ph_adam(SMem& sm, const float* Kb, const float* yc, const float* alpha,
                        float* scal, int n, int tstep, int nblk) {
  int tid = threadIdx.x;
  for (int job = blockIdx.x; job < 8; job += nblk) {
    int m = job;
    const float* G = Kb + (size_t)m * 1048576;
    const float* y = yc + (size_t)m * NC;
    float* s = scal + m * 32;
    float cm = s[3];
    float t3 = 0, t4 = 0, t5 = 0, t6 = 0;
    for (int i = tid; i < n; i += 256) {
      float a = alpha[m * 1024 + i];
      t3 += G[(size_t)i * n + i];
      t4 = fmaf(a, a, t4);
      t5 += a;
      t6 = fmaf(y[i] - cm, a, t6);
    }
    for (int off = 32; off; off >>= 1) {
      t3 += __shfl_down(t3, off); t4 += __shfl_down(t4, off);
      t5 += __shfl_down(t5, off); t6 += __shfl_down(t6, off);
    }
    int wid = tid >> 6, lane = tid & 63;
    __syncthreads();
    if (lane == 0) { sm.red[wid][0] = t3; sm.red[wid][1] = t4; sm.red[wid][2] = t5; sm.red[wid][3] = t6; }
    __syncthreads();
    if (tid == 0) {
      t3 = sm.red[0][0] + sm.red[1][0] + sm.red[2][0] + sm.red[3][0];
      t4 = sm.red[0][1] + sm.red[1][1] + sm.red[2][1] + sm.red[3][1];
      t5 = sm.red[0][2] + sm.red[1][2] + sm.red[2][2] + sm.red[3][2];
      t6 = sm.red[0][3] + sm.red[1][3] + sm.red[2][3] + sm.red[3][3];
      float T1 = s[15], T2 = s[16];
      float ls = s[12], os = s[13], noi = s[14];
      float fn = (float)n;
      float g_ls = 0.5f / fn * (T1 - T2);
      float g_os = 0.5f / (fn * os) * (fn - noi * t3 - t6 + noi * t4);
      float g_no = 0.5f / fn * (t3 - t4);
      float g_c  = -t5 / fn;
      float gr[4];
      gr[0] = g_ls * sigmf(s[0]);
      gr[1] = g_os * sigmf(s[1]);
      gr[2] = g_no * sigmf(s[2]);
      gr[3] = g_c;
      float bc1 = 1.0f - powf(0.9f, (float)tstep);
      float bc2 = 1.0f - powf(0.999f, (float)tstep);
#pragma unroll
      for (int i = 0; i < 4; ++i) {
        float mv = 0.9f * s[4 + i] + 0.1f * gr[i];
        float vv = 0.999f * s[8 + i] + 0.001f * gr[i] * gr[i];
        s[4 + i] = mv; s[8 + i] = vv;
        s[i] = s[i] - 0.1f * (mv / bc1) / (sqrtf(vv / bc2) + 1e-8f);
      }
      s[12] = softplusf(s[0]);
      s[13] = softplusf(s[1]);
      s[14] = softplusf(s[2]) + 1e-4f;
    }
  }
}

// prediction kernels
__device__ void ph_buildKtc(SMem& sm, const float* xt, const float* xc, float* Ktc,
                            const float* scal, int nblk) {
  int tid = threadIdx.x;
  int njobs = 8 * 8 * 16;  // m x (NT/64) x (NC/64)
  for (int job = blockIdx.x; job < njobs; job += nblk) {
    int m = job & 7, q = job >> 3;
    int ti = q / 16, tj = q % 16;
    const float* s = scal + m * 32;
    float ls = s[12], os = s[13];
    float il2 = 1.0f / (ls * ls);
    __syncthreads();
    if (tid < 64) {
      int r = ti * 64 + tid;
      sm.xi[tid][0] = xt[(size_t)m * NT * 3 + r * 3 + 0];
      sm.xi[tid][1] = xt[(size_t)m * NT * 3 + r * 3 + 1];
      sm.xi[tid][2] = xt[(size_t)m * NT * 3 + r * 3 + 2];
    } else if (tid < 128) {
      int lr = tid - 64; int r = tj * 64 + lr;
      sm.xj[lr][0] = xc[(size_t)m * NC * 3 + r * 3 + 0];
      sm.xj[lr][1] = xc[(size_t)m * NC * 3 + r * 3 + 1];
      sm.xj[lr][2] = xc[(size_t)m * NC * 3 + r * 3 + 2];
    }
    __syncthreads();
    for (int e = tid; e < 4096; e += 256) {
      int r = e >> 6, c = e & 63;
      float d0 = sm.xi[r][0] - sm.xj[c][0], d1 = sm.xi[r][1] - sm.xj[c][1], d2 = sm.xi[r][2] - sm.xj[c][2];
      float r2 = d0 * d0 + d1 * d1 + d2 * d2;
      float z = fmaxf(r2 * il2, 1e-12f);
      float dd = sqrtf(z);
      float kv = os * (1.0f + S5 * dd + (5.0f / 3.0f) * z) * expf(-S5 * dd);
      Ktc[(size_t)m * NT * NC + (size_t)(ti * 64 + r) * NC + tj * 64 + c] = kv;
    }
  }
}

__device__ void ph_predW(SMem& sm, const float* Ktc, const float* Kb, float* Wb, int nblk) {
  int tx = threadIdx.x & 15, ty = threadIdx.x >> 4;
  int njobs = 8 * 8 * 16;
  for (int job = blockIdx.x; job < njobs; job += nblk) {
    int m = job & 7, q = job >> 3;
    int ti = q / 16, tj = q % 16;
    float acc[4][4] = {};
    gemm64<0, 0>(Ktc + (size_t)m * NT * NC + (size_t)(ti * 64) * NC, NC,
                 Kb + (size_t)m * 1048576 + tj * 64, 1024, 0, 1024, acc, sm);
    float* C = Wb + (size_t)m * NT * NC + (size_t)(ti * 64) * NC + tj * 64;
#pragma unroll
    for (int ii = 0; ii < 4; ++ii)
#pragma unroll
      for (int jj = 0; jj < 4; ++jj) C[(size_t)(ty * 4 + ii) * NC + tx * 4 + jj] = acc[ii][jj];
  }
}

__device__ void ph_meanvar(SMem& sm, const float* Ktc, const float* Wb, const float* alpha,
                           const float* scal, float* out, int nblk) {
  int tid = threadIdx.x;
  int njobs = MM * NT;
  for (int job = blockIdx.x; job < njobs; job += nblk) {
    int m = job >> 9, t = job & 511;
    const float* kr = Ktc + (size_t)m * NT * NC + (size_t)t * NC;
    const float* wr = Wb + (size_t)m * NT * NC + (size_t)t * NC;
    const float* al = alpha + m * 1024;
    float s1 = 0.0f, s2 = 0.0f;
    for (int c = tid; c < NC; c += 256) {
      float kv = kr[c];
      s1 = fmaf(kv, al[c], s1);
      s2 = fmaf(kv, wr[c], s2);
    }
    for (int off = 32; off; off >>= 1) { s1 += __shfl_down(s1, off); s2 += __shfl_down(s2, off); }
    int wid = tid >> 6, lane = tid & 63;
    __syncthreads();
    if (lane == 0) { sm.red[wid][0] = s1; sm.red[wid][1] = s2; }
    __syncthreads();
    if (tid == 0) {
      s1 = sm.red[0][0] + sm.red[1][0] + sm.red[2][0] + sm.red[3][0];
      s2 = sm.red[0][1] + sm.red[1][1] + sm.red[2][1] + sm.red[3][1];
      const float* s = scal + m * 32;
      out[(size_t)m * NT + t] = s[3] + s1;
      out[(size_t)MM * NT + (size_t)m * NT + t] = s[13] + s[14] - s2;
    }
  }
}

// ---------------- mega kernel: entire pipeline, one launch ----------------
__global__ void __launch_bounds__(256, 2)
mega(const float* xc, const float* yc, const float* xt, float* out, float* ws, int nblk) {
  __shared__ SMem sm;
  float* Kb    = ws;
  float* Ab    = ws + OFF_A;
  float* Tb    = ws + OFF_T;
  float* Ktc   = ws + OFF_KTC;
  float* alpha = ws + OFF_ALPHA;
  float* scal  = ws + OFF_SCAL;
  unsigned* bar = (unsigned*)(ws + OFF_BAR);
  float* Wb = Ab;  // Ab dead after the final syrk

  int epoch = 0;
  for (int step = 0; step < 17; ++step) {
    int n = step < 8 ? 512 : 1024;
    int nb = n >> 6;

    ph_buildK(sm, xc, Kb, scal, alpha, scal, n, nb, nblk);
    gbar(bar, nblk, epoch);

    for (int k = 0; k < nb; ++k) {
      ph_diag(sm, Kb, Ab, k, n, nblk);
      gbar(bar, nblk, epoch);
      int t = nb - 1 - k;
      if (t > 0) {
        ph_panel(sm, Kb, Ab, k, n, t, nblk);
        gbar(bar, nblk, epoch);
        ph_trail(sm, Kb, k, n, t, nblk);
        gbar(bar, nblk, epoch);
      }
    }
    for (int s = 64; s < n; s <<= 1) {
      ph_trinvT(sm, Kb, Ab, Tb, s, n, nblk);
      gbar(bar, nblk, epoch);
      ph_trinvA(sm, Ab, Tb, s, n, nblk);
      gbar(bar, nblk, epoch);
    }
    ph_syrk(sm, Ab, Kb, n, nb, nblk);
    gbar(bar, nblk, epoch);
    ph_alpha(sm, Kb, yc, scal, alpha, n, nb, nblk);
    gbar(bar, nblk, epoch);

    if (step < 16) {
      ph_reduce(sm, Kb, xc, alpha, scal, n, nb, nblk);
      gbar(bar, nblk, epoch);
      ph_adam(sm, Kb, yc, alpha, scal, n, step + 1, nblk);
      gbar(bar, nblk, epoch);
    }
  }

  ph_buildKtc(sm, xt, xc, Ktc, scal, nblk);
  gbar(bar, nblk, epoch);
  ph_predW(sm, Ktc, Kb, Wb, nblk);
  gbar(bar, nblk, epoch);
  ph_meanvar(sm, Ktc, Wb, alpha, scal, out, nblk);
}

// ---------------- init ----------------
__global__ void k_init(float* scal, unsigned* bar) {
  int t = threadIdx.x;
  if (t < MM) {
    float* s = scal + t * 32;
    for (int i = 0; i < 12; ++i) s[i] = 0.0f;
    float sp0 = 0.69314718056f;  // softplus(0)
    s[12] = sp0; s[13] = sp0; s[14] = sp0 + 1e-4f;
    s[15] = 0.0f; s[16] = 0.0f;
  }
  for (int i = t; i < 512; i += 256) bar[i] = 0u;
}

// ---------------- host ----------------
extern "C" void kernel_launch(void* const* d_in, const int* in_sizes, int n_in,
                              void* d_out, int out_size, void* d_ws, size_t ws_size,
                              hipStream_t stream) {
  const float* xc = (const float*)d_in[0];
  const float* yc = (const float*)d_in[1];
  const float* xt = (const float*)d_in[2];
  float* out = (float*)d_out;
  float* ws = (float*)d_ws;
  float* scal = ws + OFF_SCAL;
  unsigned* bar = (unsigned*)(ws + OFF_BAR);

  k_init<<<dim3(1), dim3(256), 0, stream>>>(scal, bar);

  // grid: multiple of 16, guaranteed co-resident (LDS ~47.5KB -> >=2 blocks/CU)
  int maxb = 0;
  hipError_t qe = hipOccupancyMaxActiveBlocksPerMultiprocessor(&maxb, mega, 256, 0);
  int grid = 256;
  if (qe == hipSuccess && maxb >= 2) grid = 512;

  void* args[6];
  args[0] = (void*)&xc; args[1] = (void*)&yc; args[2] = (void*)&xt;
  args[3] = (void*)&out; args[4] = (void*)&ws; args[5] = (void*)&grid;
  hipError_t le = hipLaunchCooperativeKernel(mega, dim3(grid), dim3(256), args, 0u, stream);
  if (le != hipSuccess) {
    (void)hipGetLastError();  // clear sticky error; fall back to plain launch
    mega<<<dim3(grid), dim3(256), 0, stream>>>(xc, yc, xt, out, ws, grid);
  }

  (void)in_sizes; (void)n_in; (void)out_size; (void)ws_size;
}